// Round 7
// baseline (2256.940 us; speedup 1.0000x reference)
//
#include <hip/hip_runtime.h>
#include <math.h>

#define E_CNT 800000
#define G_CNT 1000000
#define NUM_NODES 100000
#define NT (G_CNT / 32)        // 31250 tiles of 32 groups
#define GRID 512               // 2 blocks per CU
#define TPB 256                // 4 waves

typedef __attribute__((ext_vector_type(8))) short bf16x8;    // 8 bf16 = 4 VGPRs
typedef __attribute__((ext_vector_type(16))) float f32x16;

__device__ __forceinline__ short f2bf(float f) {
    union { float f; unsigned u; } v; v.f = f;
    unsigned r = v.u + 0x7fffu + ((v.u >> 16) & 1u);   // RNE
    return (short)(r >> 16);
}

__global__ void zero_deg_kernel(float* __restrict__ deg) {
    int i = blockIdx.x * blockDim.x + threadIdx.x;
    if (i < NUM_NODES) deg[i] = 0.0f;
}

__global__ void degree_kernel(const int* __restrict__ ei, float* __restrict__ deg) {
    int e = blockIdx.x * blockDim.x + threadIdx.x;
    if (e < E_CNT) {
        atomicAdd(&deg[ei[e]], 1.0f);
        atomicAdd(&deg[ei[E_CNT + e]], 1.0f);
    }
}

// W1T[n][k] = bf16(W1[k][n])
__global__ void prep_w1t_kernel(const float* __restrict__ W1, short* __restrict__ w1t) {
    int t = blockIdx.x * blockDim.x + threadIdx.x;   // 65536
    int n = t >> 8, k = t & 255;
    w1t[t] = f2bf(W1[k * 256 + n]);
}

// emb fp32 (800000x128) -> bf16 copy
__global__ void prep_emb_kernel(const float* __restrict__ emb, short* __restrict__ ebf) {
    long t = (long)blockIdx.x * blockDim.x + threadIdx.x;
    const float4* e4 = (const float4*)emb;
    float4 v0 = e4[t * 2], v1 = e4[t * 2 + 1];
    bf16x8 h;
    h[0] = f2bf(v0.x); h[1] = f2bf(v0.y); h[2] = f2bf(v0.z); h[3] = f2bf(v0.w);
    h[4] = f2bf(v1.x); h[5] = f2bf(v1.y); h[6] = f2bf(v1.z); h[7] = f2bf(v1.w);
    *(bf16x8*)&ebf[t * 8] = h;
}

// Persistent blocks (2/CU). MODE 2: gather bf16 table; MODE 1: fp32 emb.
// pairS swizzle: 16B chunk c of row r holds logical chunk (c ^ (r&7)).
template <int MODE>
__launch_bounds__(TPB, 2)
__global__ void egis_main_kernel(
    const float* __restrict__ emb,
    const int*   __restrict__ eg,
    const int*   __restrict__ ei,
    const float* __restrict__ b1,
    const float* __restrict__ W2, const float* __restrict__ b2,
    const float* __restrict__ Ws1, const float* __restrict__ bs1,
    const float* __restrict__ Ws2, const float* __restrict__ bs2,
    const float* __restrict__ Wc1, const float* __restrict__ bc1,
    const float* __restrict__ Wc2, const float* __restrict__ bc2,
    const float* __restrict__ deg,
    const short* __restrict__ w1t,   // (256,256) bf16 [n][k]
    const short* __restrict__ ebf,   // (E,128) bf16
    float* __restrict__ out)
{
    __shared__ short pairS[2][32][256];   // 32 KB dbuf; pair, then relu(h)
    __shared__ short w2tS[8][264];        // W2^T bf16
    __shared__ float compS[32][8];
    __shared__ float ssS[32];
    __shared__ int   gS[2][2][32];        // [buf][g0/g1][row]

    const int tid = threadIdx.x;
    const int wv = tid >> 6, lane = tid & 63;
    const int l32 = lane & 31, lh32 = lane >> 5;
    const int axr = l32 & 7;

    // ---- one-time: 64 W1T cols per wave into registers (2 x 32-col tiles) ----
    bf16x8 bReg0[16], bReg1[16];
    {
        const bf16x8* B8 = (const bf16x8*)w1t;       // 32 chunks per n-row
        const int b0 = (wv * 64 + l32) * 32 + lh32;
        const int b1i = (wv * 64 + 32 + l32) * 32 + lh32;
        #pragma unroll
        for (int ks = 0; ks < 16; ++ks) { bReg0[ks] = B8[b0 + ks * 2]; bReg1[ks] = B8[b1i + ks * 2]; }
    }
    const float b1v0 = b1[wv * 64 + l32];
    const float b1v1 = b1[wv * 64 + 32 + l32];
    #pragma unroll
    for (int it = 0; it < 2048 / TPB; ++it) {        // W2 (256x8) -> w2tS
        int idx = it * TPB + tid;                    // k*8+n
        w2tS[idx & 7][idx >> 3] = f2bf(W2[idx]);
    }

    // ---- prologue ----
    int t = blockIdx.x;
    if (tid < 32) {
        int2 g = ((const int2*)eg)[t * 32 + tid];
        gS[0][0][tid] = g.x; gS[0][1][tid] = g.y;
    }
    __syncthreads();

    bf16x8 gReg[4];
    float4 gRegF[4][2];
    #pragma unroll
    for (int it = 0; it < 4; ++it) {
        int idx = it * TPB + tid;                    // row*32 + chunk
        int r = idx >> 5, rc = idx & 31;
        int gi = rc ^ (r & 7);
        int grow = (gi & 16) ? gS[0][1][r] : gS[0][0][r];
        if constexpr (MODE == 2) {
            gReg[it] = *(const bf16x8*)(ebf + (long)grow * 128 + (gi & 15) * 8);
        } else {
            const float4* s4 = (const float4*)(emb + (long)grow * 128 + (gi & 15) * 8);
            gRegF[it][0] = s4[0]; gRegF[it][1] = s4[1];
        }
    }
    int2 egReg = {0, 0};
    {
        int tn = (t + GRID < NT) ? t + GRID : NT - 1;
        if (tid < 32) egReg = ((const int2*)eg)[tn * 32 + tid];
    }

    int cur = 0;
    while (t < NT) {
        const int nxt = cur ^ 1;

        // ---- phase A: commit gathered pair(t); publish indices(t+GRID) ----
        #pragma unroll
        for (int it = 0; it < 4; ++it) {
            int idx = it * TPB + tid;
            int r = idx >> 5, rc = idx & 31;
            if constexpr (MODE == 2) {
                *(bf16x8*)&pairS[cur][r][rc * 8] = gReg[it];
            } else {
                float4 v0 = gRegF[it][0], v1 = gRegF[it][1];
                bf16x8 h;
                h[0] = f2bf(v0.x); h[1] = f2bf(v0.y); h[2] = f2bf(v0.z); h[3] = f2bf(v0.w);
                h[4] = f2bf(v1.x); h[5] = f2bf(v1.y); h[6] = f2bf(v1.z); h[7] = f2bf(v1.w);
                *(bf16x8*)&pairS[cur][r][rc * 8] = h;
            }
        }
        if (tid < 32) { gS[nxt][0][tid] = egReg.x; gS[nxt][1][tid] = egReg.y; }
        __syncthreads();

        // ---- phase B ----
        // wave 1: issue ei FIRST (so deg issue later doesn't drain gathers)
        int eiv0 = 0, eiv1 = 0;
        if (wv == 1) {
            int r = lane >> 1, p = lane & 1;
            int node = p ? gS[cur][1][r] : gS[cur][0][r];
            eiv0 = ei[node];
            eiv1 = ei[E_CNT + node];
        }
        // all: issue gather(t+GRID)
        #pragma unroll
        for (int it = 0; it < 4; ++it) {
            int idx = it * TPB + tid;
            int r = idx >> 5, rc = idx & 31;
            int gi = rc ^ (r & 7);
            int grow = (gi & 16) ? gS[nxt][1][r] : gS[nxt][0][r];
            if constexpr (MODE == 2) {
                gReg[it] = *(const bf16x8*)(ebf + (long)grow * 128 + (gi & 15) * 8);
            } else {
                const float4* s4 = (const float4*)(emb + (long)grow * 128 + (gi & 15) * 8);
                gRegF[it][0] = s4[0]; gRegF[it][1] = s4[1];
            }
        }
        {   // eg prefetch for t+2*GRID
            int tn2 = (t + 2 * GRID < NT) ? t + 2 * GRID : NT - 1;
            if (tid < 32) egReg = ((const int2*)eg)[tn2 * 32 + tid];
        }

        // main MFMA: one A-read feeds two independent 32x32 chains
        f32x16 acc0, acc1;
        #pragma unroll
        for (int i = 0; i < 16; ++i) { acc0[i] = b1v0; acc1[i] = b1v1; }
        {
            const short* aRow = &pairS[cur][l32][0];
            #pragma unroll
            for (int ks = 0; ks < 16; ++ks) {
                bf16x8 a = *(const bf16x8*)(aRow + (((ks * 2 + lh32) ^ axr)) * 8);
                acc0 = __builtin_amdgcn_mfma_f32_32x32x16_bf16(a, bReg0[ks], acc0, 0, 0, 0);
                acc1 = __builtin_amdgcn_mfma_f32_32x32x16_bf16(a, bReg1[ks], acc1, 0, 0, 0);
            }
        }
        __syncthreads();   // pairS[cur] reads done

        // ---- phase C: store relu(h); wave 1 issues deg loads ----
        #pragma unroll
        for (int g = 0; g < 4; ++g) {
            #pragma unroll
            for (int i = 0; i < 4; ++i) {
                int row = g * 8 + lh32 * 4 + i;        // D: row=(reg&3)+8*(reg>>2)+4*(lane>>5)
                int c0 = wv * 64 + l32;
                int c1 = wv * 64 + 32 + l32;
                int sw = (row & 7) << 3;
                pairS[cur][row][c0 ^ sw] = f2bf(fmaxf(acc0[g * 4 + i], 0.f));
                pairS[cur][row][c1 ^ sw] = f2bf(fmaxf(acc1[g * 4 + i], 0.f));
            }
        }
        float dg0 = 0.f, dg1 = 0.f;
        if (wv == 1) { dg0 = deg[eiv0]; dg1 = deg[eiv1]; }   // waits ei only (vmcnt(4))
        __syncthreads();   // h tile visible

        // ---- phase D: wave 0 -> comp MFMA; wave 1 -> ss MLP ----
        if (wv == 0) {
            float c0 = (l32 < 8) ? b2[l32] : 0.f;
            f32x16 a2;
            #pragma unroll
            for (int i = 0; i < 16; ++i) a2[i] = c0;
            const short* hRow = &pairS[cur][l32][0];
            const short* w2row = &w2tS[l32 & 7][0];
            #pragma unroll
            for (int ks = 0; ks < 16; ++ks) {
                bf16x8 a = *(const bf16x8*)(hRow + (((ks * 2 + lh32) ^ axr)) * 8);
                bf16x8 b = *(const bf16x8*)(w2row + (ks * 2 + lh32) * 8);
                a2 = __builtin_amdgcn_mfma_f32_32x32x16_bf16(a, b, a2, 0, 0, 0);
            }
            if (l32 < 8) {
                #pragma unroll
                for (int g = 0; g < 4; ++g)
                    #pragma unroll
                    for (int i = 0; i < 4; ++i)
                        compS[g * 8 + lh32 * 4 + i][l32] = fmaxf(a2[g * 4 + i], 0.f);
            }
        } else if (wv == 1) {
            // lane 2r: (s0,s1)=deg of g0's endpoints; lane 2r+1: (s2,s3)
            float o0 = __shfl_xor(dg0, 1), o1 = __shfl_xor(dg1, 1);
            int p = lane & 1;
            float s0 = p ? o0 : dg0, s1 = p ? o1 : dg1;
            float s2 = p ? dg0 : o0, s3 = p ? dg1 : o1;
            float part = 0.f;
            #pragma unroll
            for (int i = 0; i < 32; ++i) {
                int u = p * 32 + i;
                float h = bs1[u] + s0 * Ws1[u] + s1 * Ws1[64 + u]
                                 + s2 * Ws1[128 + u] + s3 * Ws1[192 + u];
                part += fmaxf(h, 0.f) * Ws2[u];
            }
            part += __shfl_xor(part, 1);
            if (p == 0) ssS[lane >> 1] = part + bs2[0];
        }
        __syncthreads();   // compS + ssS visible

        // ---- phase E: head MLP, 8 threads per group-row ----
        {
            int r = tid >> 3, q = tid & 7;
            float as[8];
            #pragma unroll
            for (int a = 0; a < 8; ++a) as[a] = compS[r][a];
            float ssv = ssS[r];
            float p2 = 0.f;
            #pragma unroll
            for (int i = 0; i < 16; ++i) {
                int u = q * 16 + i;
                float h = bc1[u];
                #pragma unroll
                for (int a = 0; a < 8; ++a) h += as[a] * Wc1[a * 128 + u];
                h += ssv * Wc1[1024 + u];
                p2 += fmaxf(h, 0.f) * Wc2[u];
            }
            p2 += __shfl_xor(p2, 1);
            p2 += __shfl_xor(p2, 2);
            p2 += __shfl_xor(p2, 4);
            if (q == 0) out[t * 32 + r] = 1.f / (1.f + expf(-(p2 + bc2[0])));
        }

        cur = nxt;
        t += GRID;
    }
}

extern "C" void kernel_launch(void* const* d_in, const int* in_sizes, int n_in,
                              void* d_out, int out_size, void* d_ws, size_t ws_size,
                              hipStream_t stream) {
    const float* emb = (const float*)d_in[0];
    const int*   eg  = (const int*)d_in[1];
    const int*   ei  = (const int*)d_in[2];
    const float* W1  = (const float*)d_in[3];
    const float* b1  = (const float*)d_in[4];
    const float* W2  = (const float*)d_in[5];
    const float* b2  = (const float*)d_in[6];
    const float* Ws1 = (const float*)d_in[7];
    const float* bs1 = (const float*)d_in[8];
    const float* Ws2 = (const float*)d_in[9];
    const float* bs2 = (const float*)d_in[10];
    const float* Wc1 = (const float*)d_in[11];
    const float* bc1 = (const float*)d_in[12];
    const float* Wc2 = (const float*)d_in[13];
    const float* bc2 = (const float*)d_in[14];
    float* out = (float*)d_out;

    // ws: deg | w1t bf16 | ebf bf16
    float* deg = (float*)d_ws;
    size_t degB = ((size_t)NUM_NODES * 4 + 255) & ~(size_t)255;
    short* w1t = (short*)((char*)d_ws + degB);
    size_t w1tB = 256 * 256 * sizeof(short);
    short* ebf = (short*)((char*)d_ws + degB + w1tB);
    size_t embB = (size_t)E_CNT * 128 * sizeof(short);

    int mode = (ws_size >= degB + w1tB + embB) ? 2 : 1;

    zero_deg_kernel<<<(NUM_NODES + 255) / 256, 256, 0, stream>>>(deg);
    degree_kernel<<<(E_CNT + 255) / 256, 256, 0, stream>>>(ei, deg);
    prep_w1t_kernel<<<65536 / 256, 256, 0, stream>>>(W1, w1t);
    if (mode == 2) {
        prep_emb_kernel<<<50000, 256, 0, stream>>>(emb, ebf);
        egis_main_kernel<2><<<GRID, TPB, 0, stream>>>(
            emb, eg, ei, b1, W2, b2, Ws1, bs1, Ws2, bs2, Wc1, bc1, Wc2, bc2,
            deg, w1t, ebf, out);
    } else {
        egis_main_kernel<1><<<GRID, TPB, 0, stream>>>(
            emb, eg, ei, b1, W2, b2, Ws1, bs1, Ws2, bs2, Wc1, bc1, Wc2, bc2,
            deg, w1t, (const short*)nullptr, out);
    }
}

// Round 8
// 1191.682 us; speedup vs baseline: 1.8939x; 1.8939x over previous
//
#include <hip/hip_runtime.h>
#include <math.h>

#define E_CNT 800000
#define G_CNT 1000000
#define NUM_NODES 100000
#define NT (G_CNT / 32)        // 31250 tiles of 32 groups
#define GRID 512               // 2 blocks per CU
#define TPB 512                // 8 waves

typedef __attribute__((ext_vector_type(8))) short bf16x8;    // 8 bf16 = 4 VGPRs
typedef __attribute__((ext_vector_type(16))) float f32x16;

__device__ __forceinline__ short f2bf(float f) {
    union { float f; unsigned u; } v; v.f = f;
    unsigned r = v.u + 0x7fffu + ((v.u >> 16) & 1u);   // RNE
    return (short)(r >> 16);
}

__global__ void zero_deg_kernel(float* __restrict__ deg) {
    int i = blockIdx.x * blockDim.x + threadIdx.x;
    if (i < NUM_NODES) deg[i] = 0.0f;
}

__global__ void degree_kernel(const int* __restrict__ ei, float* __restrict__ deg) {
    int e = blockIdx.x * blockDim.x + threadIdx.x;
    if (e < E_CNT) {
        atomicAdd(&deg[ei[e]], 1.0f);
        atomicAdd(&deg[ei[E_CNT + e]], 1.0f);
    }
}

// W1T[n][k] = bf16(W1[k][n])
__global__ void prep_w1t_kernel(const float* __restrict__ W1, short* __restrict__ w1t) {
    int t = blockIdx.x * blockDim.x + threadIdx.x;   // 65536
    int n = t >> 8, k = t & 255;
    w1t[t] = f2bf(W1[k * 256 + n]);
}

// emb fp32 (800000x128) -> bf16 copy
__global__ void prep_emb_kernel(const float* __restrict__ emb, short* __restrict__ ebf) {
    long t = (long)blockIdx.x * blockDim.x + threadIdx.x;
    const float4* e4 = (const float4*)emb;
    float4 v0 = e4[t * 2], v1 = e4[t * 2 + 1];
    bf16x8 h;
    h[0] = f2bf(v0.x); h[1] = f2bf(v0.y); h[2] = f2bf(v0.z); h[3] = f2bf(v0.w);
    h[4] = f2bf(v1.x); h[5] = f2bf(v1.y); h[6] = f2bf(v1.z); h[7] = f2bf(v1.w);
    *(bf16x8*)&ebf[t * 8] = h;
}

// Persistent blocks, 2/CU. MODE 2: gather via global_load_lds from bf16 table.
// MODE 1: register-staged gather from fp32 emb (fallback).
// pairS swizzle: 16B chunk c of row r holds LOGICAL chunk (c ^ (r&7));
// for MODE 2 the permutation is applied to the global SOURCE address, LDS
// destination stays linear (lane-ordered) as global_load_lds requires.
template <int MODE>
__launch_bounds__(TPB, 4)
__global__ void egis_main_kernel(
    const float* __restrict__ emb,
    const int*   __restrict__ eg,
    const int*   __restrict__ ei,
    const float* __restrict__ b1,
    const float* __restrict__ W2, const float* __restrict__ b2,
    const float* __restrict__ Ws1, const float* __restrict__ bs1,
    const float* __restrict__ Ws2, const float* __restrict__ bs2,
    const float* __restrict__ Wc1, const float* __restrict__ bc1,
    const float* __restrict__ Wc2, const float* __restrict__ bc2,
    const float* __restrict__ deg,
    const short* __restrict__ w1t,   // (256,256) bf16 [n][k]
    const short* __restrict__ ebf,   // (E,128) bf16
    float* __restrict__ out)
{
    __shared__ short pairS[2][32][256];   // 32 KB dbuf; pair, then relu(h)
    __shared__ short w2tS[8][264];        // W2^T bf16
    __shared__ float compS[32][8];
    __shared__ float ssS[32];
    __shared__ int   gS[2][2][32];        // [buf][g0/g1][row]
    __shared__ float ws1S[4][64];         // tail weights, staged once
    __shared__ float bs1S[64], ws2S[64];
    __shared__ float wc1S[9][128];
    __shared__ float bc1S[128], wc2S[128];
    __shared__ float sc2S[2];             // bs2, bc2

    const int tid = threadIdx.x;
    const int wv = tid >> 6, lane = tid & 63;
    const int l32 = lane & 31, lh32 = lane >> 5;
    const int axr = l32 & 7;

    // ---- one-time: 32 W1T cols per wave into registers; small weights to LDS ----
    bf16x8 bReg[16];
    {
        const bf16x8* B8 = (const bf16x8*)w1t;       // 32 chunks per n-row
        const int bBase = (wv * 32 + l32) * 32 + lh32;
        #pragma unroll
        for (int ks = 0; ks < 16; ++ks) bReg[ks] = B8[bBase + ks * 2];
    }
    const float b1v = b1[wv * 32 + l32];
    for (int i = tid; i < 2048; i += TPB) w2tS[i & 7][i >> 3] = f2bf(W2[i]);
    if (tid < 256) ((float*)ws1S)[tid] = Ws1[tid];
    if (tid < 64)  { bs1S[tid] = bs1[tid]; ws2S[tid] = Ws2[tid]; }
    for (int i = tid; i < 1152; i += TPB) ((float*)wc1S)[i] = Wc1[i];
    if (tid < 128) { bc1S[tid] = bc1[tid]; wc2S[tid] = Wc2[tid]; }
    if (tid == 0)  { sc2S[0] = bs2[0]; sc2S[1] = bc2[0]; }

    // ---- prologue: indices + stage tile t0; eg prefetch for t0+GRID ----
    int t = blockIdx.x;
    if (tid < 32) {
        int2 g = ((const int2*)eg)[t * 32 + tid];
        gS[0][0][tid] = g.x; gS[0][1][tid] = g.y;
    }
    __syncthreads();

    float4 gRegF[2][2];    // MODE 1 only
    if constexpr (MODE == 2) {
        short* dst = &pairS[0][0][0];
        #pragma unroll
        for (int it = 0; it < 2; ++it) {
            int idx = it * TPB + tid;                // row*32 + chunk
            int r = idx >> 5, rc = idx & 31;
            int gi = rc ^ (r & 7);
            int grow = (gi & 16) ? gS[0][1][r] : gS[0][0][r];
            const short* src = ebf + (long)grow * 128 + (gi & 15) * 8;
            __builtin_amdgcn_global_load_lds(
                (const __attribute__((address_space(1))) void*)src,
                (__attribute__((address_space(3))) void*)(dst + idx * 8), 16, 0, 0);
        }
    } else {
        #pragma unroll
        for (int it = 0; it < 2; ++it) {
            int idx = it * TPB + tid;
            int r = idx >> 5, rc = idx & 31;
            int gi = rc ^ (r & 7);
            int grow = (gi & 16) ? gS[0][1][r] : gS[0][0][r];
            const float4* s4 = (const float4*)(emb + (long)grow * 128 + (gi & 15) * 8);
            gRegF[it][0] = s4[0]; gRegF[it][1] = s4[1];
        }
    }
    int2 egReg = {0, 0};
    {
        int tn = (t + GRID < NT) ? t + GRID : NT - 1;
        if (tid < 32) egReg = ((const int2*)eg)[tn * 32 + tid];
    }

    int cur = 0;
    while (t < NT) {
        const int nxt = cur ^ 1;

        // ---- phase A: (MODE1: commit regs); publish indices(t+GRID) ----
        if constexpr (MODE == 1) {
            #pragma unroll
            for (int it = 0; it < 2; ++it) {
                int idx = it * TPB + tid;
                int r = idx >> 5, rc = idx & 31;
                float4 v0 = gRegF[it][0], v1 = gRegF[it][1];
                bf16x8 h;
                h[0] = f2bf(v0.x); h[1] = f2bf(v0.y); h[2] = f2bf(v0.z); h[3] = f2bf(v0.w);
                h[4] = f2bf(v1.x); h[5] = f2bf(v1.y); h[6] = f2bf(v1.z); h[7] = f2bf(v1.w);
                *(bf16x8*)&pairS[cur][r][rc * 8] = h;
            }
        }
        if (tid < 32) { gS[nxt][0][tid] = egReg.x; gS[nxt][1][tid] = egReg.y; }
        __syncthreads();   // b1: gS[nxt] (and tile-t data) visible

        // ---- phase B ----
        // wave 1: issue ei FIRST (deg consume later won't drain gathers)
        int eiv0 = 0, eiv1 = 0;
        if (wv == 1) {
            int r = lane >> 1, p = lane & 1;
            int node = p ? gS[cur][1][r] : gS[cur][0][r];
            eiv0 = ei[node];
            eiv1 = ei[E_CNT + node];
        }
        // all: stage tile t+GRID into buf[nxt]
        if constexpr (MODE == 2) {
            short* dst = &pairS[nxt][0][0];
            #pragma unroll
            for (int it = 0; it < 2; ++it) {
                int idx = it * TPB + tid;
                int r = idx >> 5, rc = idx & 31;
                int gi = rc ^ (r & 7);
                int grow = (gi & 16) ? gS[nxt][1][r] : gS[nxt][0][r];
                const short* src = ebf + (long)grow * 128 + (gi & 15) * 8;
                __builtin_amdgcn_global_load_lds(
                    (const __attribute__((address_space(1))) void*)src,
                    (__attribute__((address_space(3))) void*)(dst + idx * 8), 16, 0, 0);
            }
        } else {
            #pragma unroll
            for (int it = 0; it < 2; ++it) {
                int idx = it * TPB + tid;
                int r = idx >> 5, rc = idx & 31;
                int gi = rc ^ (r & 7);
                int grow = (gi & 16) ? gS[nxt][1][r] : gS[nxt][0][r];
                const float4* s4 = (const float4*)(emb + (long)grow * 128 + (gi & 15) * 8);
                gRegF[it][0] = s4[0]; gRegF[it][1] = s4[1];
            }
        }
        {   // eg prefetch for t+2*GRID
            int tn2 = (t + 2 * GRID < NT) ? t + 2 * GRID : NT - 1;
            if (tid < 32) egReg = ((const int2*)eg)[tn2 * 32 + tid];
        }

        // ---- main MFMA: 32x32 C-tile per wave over buf[cur] ----
        f32x16 acc;
        #pragma unroll
        for (int i = 0; i < 16; ++i) acc[i] = b1v;
        {
            const short* aRow = &pairS[cur][l32][0];
            #pragma unroll
            for (int ks = 0; ks < 16; ++ks) {
                bf16x8 a = *(const bf16x8*)(aRow + (((ks * 2 + lh32) ^ axr)) * 8);
                acc = __builtin_amdgcn_mfma_f32_32x32x16_bf16(a, bReg[ks], acc, 0, 0, 0);
            }
        }
        __syncthreads();   // b2: pairS[cur] reads done (drains staging loads too)

        // ---- phase C: store relu(h) into buf[cur]; wave 1 issues deg ----
        #pragma unroll
        for (int g = 0; g < 4; ++g) {
            #pragma unroll
            for (int i = 0; i < 4; ++i) {
                int row = g * 8 + lh32 * 4 + i;        // D: row=(reg&3)+8*(reg>>2)+4*(lane>>5)
                int col = wv * 32 + l32;               //    col=lane&31
                pairS[cur][row][col ^ ((row & 7) << 3)] = f2bf(fmaxf(acc[g * 4 + i], 0.f));
            }
        }
        float dg0 = 0.f, dg1 = 0.f;
        if (wv == 1) { dg0 = deg[eiv0]; dg1 = deg[eiv1]; }
        __syncthreads();   // b3: h tile visible

        // ---- phase D: wave 0 -> comp MFMA; wave 1 -> ss MLP ----
        if (wv == 0) {
            float c0 = (l32 < 8) ? b2[l32] : 0.f;
            f32x16 a2;
            #pragma unroll
            for (int i = 0; i < 16; ++i) a2[i] = c0;
            const short* hRow = &pairS[cur][l32][0];
            const short* w2row = &w2tS[l32 & 7][0];
            #pragma unroll
            for (int ks = 0; ks < 16; ++ks) {
                bf16x8 a = *(const bf16x8*)(hRow + (((ks * 2 + lh32) ^ axr)) * 8);
                bf16x8 b = *(const bf16x8*)(w2row + (ks * 2 + lh32) * 8);
                a2 = __builtin_amdgcn_mfma_f32_32x32x16_bf16(a, b, a2, 0, 0, 0);
            }
            if (l32 < 8) {
                #pragma unroll
                for (int g = 0; g < 4; ++g)
                    #pragma unroll
                    for (int i = 0; i < 4; ++i)
                        compS[g * 8 + lh32 * 4 + i][l32] = fmaxf(a2[g * 4 + i], 0.f);
            }
        } else if (wv == 1) {
            // lane 2r: deg of g0's endpoints; lane 2r+1: deg of g1's
            float o0 = __shfl_xor(dg0, 1), o1 = __shfl_xor(dg1, 1);
            int p = lane & 1;
            float s0 = p ? o0 : dg0, s1 = p ? o1 : dg1;
            float s2 = p ? dg0 : o0, s3 = p ? dg1 : o1;
            float part = 0.f;
            #pragma unroll
            for (int i = 0; i < 32; ++i) {
                int u = p * 32 + i;
                float h = bs1S[u] + s0 * ws1S[0][u] + s1 * ws1S[1][u]
                                  + s2 * ws1S[2][u] + s3 * ws1S[3][u];
                part += fmaxf(h, 0.f) * ws2S[u];
            }
            part += __shfl_xor(part, 1);
            if (p == 0) ssS[lane >> 1] = part + sc2S[0];
        }
        __syncthreads();   // b4: compS + ssS visible

        // ---- phase E: head MLP, 16 threads per group-row, weights from LDS ----
        {
            int r = tid >> 4, q = tid & 15;
            float as[8];
            #pragma unroll
            for (int a = 0; a < 8; ++a) as[a] = compS[r][a];
            float ssv = ssS[r];
            float p2 = 0.f;
            #pragma unroll
            for (int i = 0; i < 8; ++i) {
                int u = q * 8 + i;
                float h = bc1S[u];
                #pragma unroll
                for (int a = 0; a < 8; ++a) h += as[a] * wc1S[a][u];
                h += ssv * wc1S[8][u];
                p2 += fmaxf(h, 0.f) * wc2S[u];
            }
            p2 += __shfl_xor(p2, 1);
            p2 += __shfl_xor(p2, 2);
            p2 += __shfl_xor(p2, 4);
            p2 += __shfl_xor(p2, 8);
            if (q == 0) out[t * 32 + r] = 1.f / (1.f + expf(-(p2 + sc2S[1])));
        }

        cur = nxt;
        t += GRID;
    }
}

extern "C" void kernel_launch(void* const* d_in, const int* in_sizes, int n_in,
                              void* d_out, int out_size, void* d_ws, size_t ws_size,
                              hipStream_t stream) {
    const float* emb = (const float*)d_in[0];
    const int*   eg  = (const int*)d_in[1];
    const int*   ei  = (const int*)d_in[2];
    const float* W1  = (const float*)d_in[3];
    const float* b1  = (const float*)d_in[4];
    const float* W2  = (const float*)d_in[5];
    const float* b2  = (const float*)d_in[6];
    const float* Ws1 = (const float*)d_in[7];
    const float* bs1 = (const float*)d_in[8];
    const float* Ws2 = (const float*)d_in[9];
    const float* bs2 = (const float*)d_in[10];
    const float* Wc1 = (const float*)d_in[11];
    const float* bc1 = (const float*)d_in[12];
    const float* Wc2 = (const float*)d_in[13];
    const float* bc2 = (const float*)d_in[14];
    float* out = (float*)d_out;

    // ws: deg | w1t bf16 | ebf bf16
    float* deg = (float*)d_ws;
    size_t degB = ((size_t)NUM_NODES * 4 + 255) & ~(size_t)255;
    short* w1t = (short*)((char*)d_ws + degB);
    size_t w1tB = 256 * 256 * sizeof(short);
    short* ebf = (short*)((char*)d_ws + degB + w1tB);
    size_t embB = (size_t)E_CNT * 128 * sizeof(short);

    int mode = (ws_size >= degB + w1tB + embB) ? 2 : 1;

    zero_deg_kernel<<<(NUM_NODES + 255) / 256, 256, 0, stream>>>(deg);
    degree_kernel<<<(E_CNT + 255) / 256, 256, 0, stream>>>(ei, deg);
    prep_w1t_kernel<<<65536 / 256, 256, 0, stream>>>(W1, w1t);
    if (mode == 2) {
        prep_emb_kernel<<<50000, 256, 0, stream>>>(emb, ebf);
        egis_main_kernel<2><<<GRID, TPB, 0, stream>>>(
            emb, eg, ei, b1, W2, b2, Ws1, bs1, Ws2, bs2, Wc1, bc1, Wc2, bc2,
            deg, w1t, ebf, out);
    } else {
        egis_main_kernel<1><<<GRID, TPB, 0, stream>>>(
            emb, eg, ei, b1, W2, b2, Ws1, bs1, Ws2, bs2, Wc1, bc1, Wc2, bc2,
            deg, w1t, (const short*)nullptr, out);
    }
}

// Round 15
// 737.901 us; speedup vs baseline: 3.0586x; 1.6150x over previous
//
#include <hip/hip_runtime.h>
#include <math.h>

#define E_CNT 800000
#define G_CNT 1000000
#define NUM_NODES 100000
#define ROWS 64
#define NT (G_CNT / ROWS)      // 15625 tiles of 64 groups
#define GRID 256               // 1 persistent block per CU
#define TPB 512                // 8 waves

typedef __attribute__((ext_vector_type(8))) short bf16x8;    // 8 bf16 = 4 VGPRs
typedef __attribute__((ext_vector_type(16))) float f32x16;

__device__ __forceinline__ short f2bf(float f) {
    union { float f; unsigned u; } v; v.f = f;
    unsigned r = v.u + 0x7fffu + ((v.u >> 16) & 1u);   // RNE
    return (short)(r >> 16);
}

__global__ void zero_deg_kernel(float* __restrict__ deg) {
    int i = blockIdx.x * blockDim.x + threadIdx.x;
    if (i < NUM_NODES) deg[i] = 0.0f;
}

__global__ void degree_kernel(const int* __restrict__ ei, float* __restrict__ deg) {
    int e = blockIdx.x * blockDim.x + threadIdx.x;
    if (e < E_CNT) {
        atomicAdd(&deg[ei[e]], 1.0f);
        atomicAdd(&deg[ei[E_CNT + e]], 1.0f);
    }
}

// W1T[n][k] = bf16(W1[k][n])
__global__ void prep_w1t_kernel(const float* __restrict__ W1, short* __restrict__ w1t) {
    int t = blockIdx.x * blockDim.x + threadIdx.x;   // 65536
    int n = t >> 8, k = t & 255;
    w1t[t] = f2bf(W1[k * 256 + n]);
}

// emb fp32 (800000x128) -> bf16 copy
__global__ void prep_emb_kernel(const float* __restrict__ emb, short* __restrict__ ebf) {
    long t = (long)blockIdx.x * blockDim.x + threadIdx.x;
    const float4* e4 = (const float4*)emb;
    float4 v0 = e4[t * 2], v1 = e4[t * 2 + 1];
    bf16x8 h;
    h[0] = f2bf(v0.x); h[1] = f2bf(v0.y); h[2] = f2bf(v0.z); h[3] = f2bf(v0.w);
    h[4] = f2bf(v1.x); h[5] = f2bf(v1.y); h[6] = f2bf(v1.z); h[7] = f2bf(v1.w);
    *(bf16x8*)&ebf[t * 8] = h;
}

// Persistent blocks, 1/CU, cap-256 VGPR. All barriers __syncthreads().
// pairS swizzle: 16B chunk c of row r holds LOGICAL chunk (c ^ (r&7));
// MODE 2 applies the permutation on the global SOURCE address so the
// global_load_lds LDS destination stays linear. MODE 1: reg-staged fp32.
template <int MODE>
__launch_bounds__(TPB, 2)
__global__ void egis_main_kernel(
    const float* __restrict__ emb,
    const int*   __restrict__ eg,
    const int*   __restrict__ ei,
    const float* __restrict__ b1,
    const float* __restrict__ W2, const float* __restrict__ b2,
    const float* __restrict__ Ws1, const float* __restrict__ bs1,
    const float* __restrict__ Ws2, const float* __restrict__ bs2,
    const float* __restrict__ Wc1, const float* __restrict__ bc1,
    const float* __restrict__ Wc2, const float* __restrict__ bc2,
    const float* __restrict__ deg,
    const short* __restrict__ w1t,   // (256,256) bf16 [n][k]
    const short* __restrict__ ebf,   // (E,128) bf16
    float* __restrict__ out)
{
    __shared__ short pairS[2][ROWS][256];  // 64 KB dbuf; pair, then relu(h)
    __shared__ short w2tS[8][264];         // W2^T bf16
    __shared__ float compS[ROWS][8];
    __shared__ float ssS[ROWS];
    __shared__ int   gS[2][2][ROWS];       // [buf][g0/g1][row]
    __shared__ float ws1S[4][64];
    __shared__ float bs1S[64], ws2S[64];

    const int tid = threadIdx.x;
    const int wv = tid >> 6, lane = tid & 63;
    const int l32 = lane & 31, lh32 = lane >> 5;
    const int axr = l32 & 7;

    // ---- one-time: W1T cols into regs; tail weights into regs/LDS ----
    bf16x8 bReg[16];
    {
        const bf16x8* B8 = (const bf16x8*)w1t;       // 32 chunks per n-row
        const int bBase = (wv * 32 + l32) * 32 + lh32;
        #pragma unroll
        for (int ks = 0; ks < 16; ++ks) bReg[ks] = B8[bBase + ks * 2];
    }
    const float b1v = b1[wv * 32 + l32];
    const float b2v = (l32 < 8) ? b2[l32] : 0.f;
    // head-MLP weights: lane owns output units 2*lane, 2*lane+1 (static idx)
    float wc1v[9][2], bc1v[2], wc2v[2];
    #pragma unroll
    for (int a = 0; a < 9; ++a) {
        wc1v[a][0] = Wc1[a * 128 + lane * 2];
        wc1v[a][1] = Wc1[a * 128 + lane * 2 + 1];
    }
    bc1v[0] = bc1[lane * 2];  bc1v[1] = bc1[lane * 2 + 1];
    wc2v[0] = Wc2[lane * 2];  wc2v[1] = Wc2[lane * 2 + 1];
    const float bs2v = bs2[0], bc2v = bc2[0];

    for (int i = tid; i < 2048; i += TPB) w2tS[i & 7][i >> 3] = f2bf(W2[i]);
    if (tid < 256) ((float*)ws1S)[tid] = Ws1[tid];
    if (tid < 64)  { bs1S[tid] = bs1[tid]; ws2S[tid] = Ws2[tid]; }

    // ---- prologue: indices + stage tile t0; eg prefetch for t0+GRID ----
    int t = blockIdx.x;
    if (tid < ROWS) {
        int2 g = ((const int2*)eg)[t * ROWS + tid];
        gS[0][0][tid] = g.x; gS[0][1][tid] = g.y;
    }
    __syncthreads();

    float4 gRegF[4][2];    // MODE 1 only
    if constexpr (MODE == 2) {
        short* dst = &pairS[0][0][0];
        #pragma unroll
        for (int it = 0; it < 4; ++it) {
            int idx = it * TPB + tid;                // row*32 + chunk
            int r = idx >> 5, rc = idx & 31;
            int gi = rc ^ (r & 7);
            int grow = (gi & 16) ? gS[0][1][r] : gS[0][0][r];
            const short* src = ebf + (long)grow * 128 + (gi & 15) * 8;
            __builtin_amdgcn_global_load_lds(
                (const __attribute__((address_space(1))) void*)src,
                (__attribute__((address_space(3))) void*)(dst + idx * 8), 16, 0, 0);
        }
    } else {
        #pragma unroll
        for (int it = 0; it < 4; ++it) {
            int idx = it * TPB + tid;
            int r = idx >> 5, rc = idx & 31;
            int gi = rc ^ (r & 7);
            int grow = (gi & 16) ? gS[0][1][r] : gS[0][0][r];
            const float4* s4 = (const float4*)(emb + (long)grow * 128 + (gi & 15) * 8);
            gRegF[it][0] = s4[0]; gRegF[it][1] = s4[1];
        }
    }
    int2 egReg = {0, 0};
    {
        int tn = (t + GRID < NT) ? t + GRID : NT - 1;
        if (tid < ROWS) egReg = ((const int2*)eg)[tn * ROWS + tid];
    }

    int cur = 0;
    while (t < NT) {
        const int nxt = cur ^ 1;

        // ---- phase A: (MODE1: commit) ; publish indices(t+GRID) ----
        if constexpr (MODE == 1) {
            #pragma unroll
            for (int it = 0; it < 4; ++it) {
                int idx = it * TPB + tid;
                int r = idx >> 5, rc = idx & 31;
                float4 v0 = gRegF[it][0], v1 = gRegF[it][1];
                bf16x8 h;
                h[0] = f2bf(v0.x); h[1] = f2bf(v0.y); h[2] = f2bf(v0.z); h[3] = f2bf(v0.w);
                h[4] = f2bf(v1.x); h[5] = f2bf(v1.y); h[6] = f2bf(v1.z); h[7] = f2bf(v1.w);
                *(bf16x8*)&pairS[cur][r][rc * 8] = h;
            }
        }
        if (tid < ROWS) { gS[nxt][0][tid] = egReg.x; gS[nxt][1][tid] = egReg.y; }
        __syncthreads();   // b1: staging(cur) drained; gS[nxt] visible

        // ---- phase B ----
        // waves 1,2: issue ei first (head of the 2-deep random chain)
        int eiv0 = 0, eiv1 = 0;
        if (wv == 1 || wv == 2) {
            int r = ((wv - 1) << 5) + (lane >> 1);
            int p = lane & 1;
            int node = p ? gS[cur][1][r] : gS[cur][0][r];
            eiv0 = ei[node];
            eiv1 = ei[E_CNT + node];
        }
        // all: stage tile t+GRID into buf[nxt]
        if constexpr (MODE == 2) {
            short* dst = &pairS[nxt][0][0];
            #pragma unroll
            for (int it = 0; it < 4; ++it) {
                int idx = it * TPB + tid;
                int r = idx >> 5, rc = idx & 31;
                int gi = rc ^ (r & 7);
                int grow = (gi & 16) ? gS[nxt][1][r] : gS[nxt][0][r];
                const short* src = ebf + (long)grow * 128 + (gi & 15) * 8;
                __builtin_amdgcn_global_load_lds(
                    (const __attribute__((address_space(1))) void*)src,
                    (__attribute__((address_space(3))) void*)(dst + idx * 8), 16, 0, 0);
            }
        } else {
            #pragma unroll
            for (int it = 0; it < 4; ++it) {
                int idx = it * TPB + tid;
                int r = idx >> 5, rc = idx & 31;
                int gi = rc ^ (r & 7);
                int grow = (gi & 16) ? gS[nxt][1][r] : gS[nxt][0][r];
                const float4* s4 = (const float4*)(emb + (long)grow * 128 + (gi & 15) * 8);
                gRegF[it][0] = s4[0]; gRegF[it][1] = s4[1];
            }
        }
        {   // eg prefetch for t+2*GRID
            int tn2 = (t + 2 * GRID < NT) ? t + 2 * GRID : NT - 1;
            if (tid < ROWS) egReg = ((const int2*)eg)[tn2 * ROWS + tid];
        }

        // ---- main MFMA: two 32x32 row-tiles per wave (2 indep chains) ----
        f32x16 acc0, acc1;
        #pragma unroll
        for (int i = 0; i < 16; ++i) { acc0[i] = b1v; acc1[i] = b1v; }
        {
            const short* aRow0 = &pairS[cur][l32][0];
            const short* aRow1 = &pairS[cur][32 + l32][0];
            #pragma unroll
            for (int ks = 0; ks < 16; ++ks) {
                int off = ((ks * 2 + lh32) ^ axr) * 8;
                bf16x8 a0 = *(const bf16x8*)(aRow0 + off);
                bf16x8 a1 = *(const bf16x8*)(aRow1 + off);
                acc0 = __builtin_amdgcn_mfma_f32_32x32x16_bf16(a0, bReg[ks], acc0, 0, 0, 0);
                acc1 = __builtin_amdgcn_mfma_f32_32x32x16_bf16(a1, bReg[ks], acc1, 0, 0, 0);
            }
        }
        __syncthreads();   // b2: all A-reads done

        // ---- phase C: store relu(h) in place; waves 1,2 issue deg ----
        #pragma unroll
        for (int g = 0; g < 4; ++g) {
            #pragma unroll
            for (int i = 0; i < 4; ++i) {
                int row = g * 8 + lh32 * 4 + i;        // D: row=(reg&3)+8*(reg>>2)+4*(lane>>5)
                int col = wv * 32 + l32;
                int sw = (row & 7) << 3;
                pairS[cur][row][col ^ sw] = f2bf(fmaxf(acc0[g * 4 + i], 0.f));
                pairS[cur][row + 32][col ^ sw] = f2bf(fmaxf(acc1[g * 4 + i], 0.f));
            }
        }
        float dg0 = 0.f, dg1 = 0.f;
        if (wv == 1 || wv == 2) { dg0 = deg[eiv0]; dg1 = deg[eiv1]; }
        __syncthreads();   // b3: h tile visible

        // ---- phase D: waves 0,3 -> comp MFMA; waves 1,2 -> ss MLP;
        //      waves 4-7 idle (BUG FIX: was unguarded else -> OOB ssS writes) ----
        if (wv == 0 || wv == 3) {
            int rt = (wv == 3) ? 32 : 0;
            f32x16 a2, a2b;
            #pragma unroll
            for (int i = 0; i < 16; ++i) { a2[i] = b2v; a2b[i] = 0.f; }
            const short* hRow = &pairS[cur][rt + l32][0];
            const short* w2row = &w2tS[l32 & 7][0];
            #pragma unroll
            for (int ks = 0; ks < 8; ++ks) {
                bf16x8 a = *(const bf16x8*)(hRow + ((ks * 2 + lh32) ^ axr) * 8);
                bf16x8 b = *(const bf16x8*)(w2row + (ks * 2 + lh32) * 8);
                a2 = __builtin_amdgcn_mfma_f32_32x32x16_bf16(a, b, a2, 0, 0, 0);
            }
            #pragma unroll
            for (int ks = 8; ks < 16; ++ks) {
                bf16x8 a = *(const bf16x8*)(hRow + ((ks * 2 + lh32) ^ axr) * 8);
                bf16x8 b = *(const bf16x8*)(w2row + (ks * 2 + lh32) * 8);
                a2b = __builtin_amdgcn_mfma_f32_32x32x16_bf16(a, b, a2b, 0, 0, 0);
            }
            if (l32 < 8) {
                #pragma unroll
                for (int g = 0; g < 4; ++g)
                    #pragma unroll
                    for (int i = 0; i < 4; ++i)
                        compS[rt + g * 8 + lh32 * 4 + i][l32] =
                            fmaxf(a2[g * 4 + i] + a2b[g * 4 + i], 0.f);
            }
        } else if (wv == 1 || wv == 2) {
            // lane 2r: deg of g0's endpoints; lane 2r+1: deg of g1's
            float o0 = __shfl_xor(dg0, 1), o1 = __shfl_xor(dg1, 1);
            int p = lane & 1;
            float s0 = p ? o0 : dg0, s1 = p ? o1 : dg1;
            float s2 = p ? dg0 : o0, s3 = p ? dg1 : o1;
            float part = 0.f;
            #pragma unroll
            for (int i = 0; i < 32; ++i) {
                int u = p * 32 + i;
                float h = bs1S[u] + s0 * ws1S[0][u] + s1 * ws1S[1][u]
                                  + s2 * ws1S[2][u] + s3 * ws1S[3][u];
                part += fmaxf(h, 0.f) * ws2S[u];
            }
            part += __shfl_xor(part, 1);
            if (p == 0) ssS[((wv - 1) << 5) + (lane >> 1)] = part + bs2v;
        }
        __syncthreads();   // b4: compS + ssS visible

        // ---- phase E: head MLP. Wave wv -> rows wv*8..wv*8+7.
        //      Lane owns units 2*lane, 2*lane+1; weights in VGPRs;
        //      activations via wave-uniform LDS broadcast. ----
        {
            #pragma unroll
            for (int rr = 0; rr < 8; ++rr) {
                int r = wv * 8 + rr;
                float ssv = ssS[r];
                float h0 = bc1v[0] + ssv * wc1v[8][0];
                float h1 = bc1v[1] + ssv * wc1v[8][1];
                #pragma unroll
                for (int a = 0; a < 8; ++a) {
                    float av = compS[r][a];
                    h0 += av * wc1v[a][0];
                    h1 += av * wc1v[a][1];
                }
                float p2 = fmaxf(h0, 0.f) * wc2v[0] + fmaxf(h1, 0.f) * wc2v[1];
                p2 += __shfl_xor(p2, 1);
                p2 += __shfl_xor(p2, 2);
                p2 += __shfl_xor(p2, 4);
                p2 += __shfl_xor(p2, 8);
                p2 += __shfl_xor(p2, 16);
                p2 += __shfl_xor(p2, 32);
                if (lane == 0) out[t * ROWS + r] = 1.f / (1.f + expf(-(p2 + bc2v)));
            }
        }

        cur = nxt;
        t += GRID;
    }
}

extern "C" void kernel_launch(void* const* d_in, const int* in_sizes, int n_in,
                              void* d_out, int out_size, void* d_ws, size_t ws_size,
                              hipStream_t stream) {
    const float* emb = (const float*)d_in[0];
    const int*   eg  = (const int*)d_in[1];
    const int*   ei  = (const int*)d_in[2];
    const float* W1  = (const float*)d_in[3];
    const float* b1  = (const float*)d_in[4];
    const float* W2  = (const float*)d_in[5];
    const float* b2  = (const float*)d_in[6];
    const float* Ws1 = (const float*)d_in[7];
    const float* bs1 = (const float*)d_in[8];
    const float* Ws2 = (const float*)d_in[9];
    const float* bs2 = (const float*)d_in[10];
    const float* Wc1 = (const float*)d_in[11];
    const float* bc1 = (const float*)d_in[12];
    const float* Wc2 = (const float*)d_in[13];
    const float* bc2 = (const float*)d_in[14];
    float* out = (float*)d_out;

    // ws: deg | w1t bf16 | ebf bf16
    float* deg = (float*)d_ws;
    size_t degB = ((size_t)NUM_NODES * 4 + 255) & ~(size_t)255;
    short* w1t = (short*)((char*)d_ws + degB);
    size_t w1tB = 256 * 256 * sizeof(short);
    short* ebf = (short*)((char*)d_ws + degB + w1tB);
    size_t embB = (size_t)E_CNT * 128 * sizeof(short);

    int mode = (ws_size >= degB + w1tB + embB) ? 2 : 1;

    zero_deg_kernel<<<(NUM_NODES + 255) / 256, 256, 0, stream>>>(deg);
    degree_kernel<<<(E_CNT + 255) / 256, 256, 0, stream>>>(ei, deg);
    prep_w1t_kernel<<<65536 / 256, 256, 0, stream>>>(W1, w1t);
    if (mode == 2) {
        prep_emb_kernel<<<50000, 256, 0, stream>>>(emb, ebf);
        egis_main_kernel<2><<<GRID, TPB, 0, stream>>>(
            emb, eg, ei, b1, W2, b2, Ws1, bs1, Ws2, bs2, Wc1, bc1, Wc2, bc2,
            deg, w1t, ebf, out);
    } else {
        egis_main_kernel<1><<<GRID, TPB, 0, stream>>>(
            emb, eg, ei, b1, W2, b2, Ws1, bs1, Ws2, bs2, Wc1, bc1, Wc2, bc2,
            deg, w1t, (const short*)nullptr, out);
    }
}